// Round 8
// baseline (94.838 us; speedup 1.0000x reference)
//
#include <hip/hip_runtime.h>
#include <hip/hip_bf16.h>

typedef __bf16 bf16x8 __attribute__((ext_vector_type(8)));
typedef __bf16 bf16x4 __attribute__((ext_vector_type(4)));
typedef float  f32x4  __attribute__((ext_vector_type(4)));

constexpr int kD  = 512;
constexpr int kBD = 64;
constexpr int kN  = 4096;
constexpr int kB  = 8;

__device__ __forceinline__ bf16x8 cvt8v(f32x4 a, f32x4 b) {
    bf16x8 r;
    r[0] = (__bf16)a[0]; r[1] = (__bf16)a[1]; r[2] = (__bf16)a[2]; r[3] = (__bf16)a[3];
    r[4] = (__bf16)b[0]; r[5] = (__bf16)b[1]; r[6] = (__bf16)b[2]; r[7] = (__bf16)b[3];
    return r;
}

// Prep: Wbk/Wbv fp32 -> bf16 ws images (blocks 0..31); block 32 zeroes S.
__global__ __launch_bounds__(256)
void lbm_prep(const float* __restrict__ Wbk, const float* __restrict__ Wbv,
              __bf16* __restrict__ wsk, __bf16* __restrict__ wsv,
              float* __restrict__ S)
{
    const int bid = blockIdx.x, t = threadIdx.x;
    if (bid < 32) {
        int i = (bid * 256 + t) * 4;
        float4 a = *(const float4*)(Wbk + i);
        float4 b = *(const float4*)(Wbv + i);
        bf16x4 ka, vb;
        ka[0]=(__bf16)a.x; ka[1]=(__bf16)a.y; ka[2]=(__bf16)a.z; ka[3]=(__bf16)a.w;
        vb[0]=(__bf16)b.x; vb[1]=(__bf16)b.y; vb[2]=(__bf16)b.z; vb[3]=(__bf16)b.w;
        *(bf16x4*)(wsk + i) = ka;
        *(bf16x4*)(wsv + i) = vb;
    } else {
        S[t * 2] = 0.f; S[t * 2 + 1] = 0.f;
    }
}

// S[b,j] = sum_n (keys[b,n,:].Wbk[j,:] + bbk[j]) * (values[b,n,:].Wbv[j,:] + bbv[j])
//
// m13-style register streaming: NO LDS data staging, no syncthreads in the
// stream. 8 waves/block = {4 j-tiles} x {K,V role}; each wave holds its 16-j
// weight tile in 64 pinned VGPRs (asm loads) and streams 64 rows via asm
// global_load_dwordx4 with a 4-slot counted-vmcnt pipeline. K-waves publish
// per-chunk projections through 4 KB LDS; raw s_barrier + lgkmcnt-only waits
// keep the next chunk's prefetch in flight across the combine.
__global__ __launch_bounds__(512, 4)
void lbm_bind(const float* __restrict__ keys, const float* __restrict__ values,
              const __bf16* __restrict__ wsk, const __bf16* __restrict__ wsv,
              const float* __restrict__ bbk,  const float* __restrict__ bbv,
              float* __restrict__ S)
{
    __shared__ float ksh[4][64][4];   // [jt][lane][4 rows] published K projections

    const int tid  = threadIdx.x;
    const int wid  = tid >> 6;
    const int ln   = tid & 63;
    const int l15  = ln & 15;
    const int lhi  = ln >> 4;
    const int role = wid & 1;          // 0 = K-projection, 1 = V-projection
    const int jt   = wid >> 1;         // j-tile 0..3
    const int jrow = jt * 16 + l15;
    const int blockRow0 = blockIdx.x * 64;

    const float*  src  = role ? values : keys;
    const __bf16* wsrc = role ? wsv    : wsk;

    // ---- weights: 16 frags (64 VGPR) via asm loads (un-sinkable) ----
#define GLDW(dst, off)                                                        \
    asm volatile("global_load_dwordx4 %0, %1, off offset:%c2"                 \
                 : "=v"(dst) : "v"(wbase), "i"(off));
    const __bf16* wbase = wsrc + jrow * kD + lhi * 8;
    bf16x8 w[16];
    GLDW(w[0],   0) GLDW(w[1],  64) GLDW(w[2],  128) GLDW(w[3],  192)
    GLDW(w[4], 256) GLDW(w[5], 320) GLDW(w[6],  384) GLDW(w[7],  448)
    GLDW(w[8], 512) GLDW(w[9], 576) GLDW(w[10], 640) GLDW(w[11], 704)
    GLDW(w[12],768) GLDW(w[13],832) GLDW(w[14], 896) GLDW(w[15], 960)
#undef GLDW
    float bk, bv;
    {
        const float* pk = bbk + jrow;
        const float* pv = bbv + jrow;
        asm volatile("global_load_dword %0, %1, off" : "=v"(bk) : "v"(pk));
        asm volatile("global_load_dword %0, %1, off" : "=v"(bv) : "v"(pv));
    }
    asm volatile("s_waitcnt vmcnt(0)" ::: "memory");
    __builtin_amdgcn_sched_barrier(0);

    // ---- streaming pipeline ----
#define GLD2(va, vb, off)                                                     \
    asm volatile("global_load_dwordx4 %0, %2, off offset:%c3\n\t"             \
                 "global_load_dwordx4 %1, %2, off offset:%c4"                 \
                 : "=v"(va), "=v"(vb)                                         \
                 : "v"(base), "i"(off), "i"((off) + 16));
#define WAITV(va, vb, n)                                                      \
    asm volatile("s_waitcnt vmcnt(" #n ")" : "+v"(va), "+v"(vb));
#define MSTEP(s, sl)                                                          \
    WAITV(a##sl, b##sl, 6)                                                    \
    acc = __builtin_amdgcn_mfma_f32_16x16x32_bf16(cvt8v(a##sl, b##sl), w[s], acc, 0, 0, 0); \
    GLD2(a##sl, b##sl, ((s) + 4) * 128)
#define MSTEPF(s, sl, n)                                                      \
    WAITV(a##sl, b##sl, n)                                                    \
    acc = __builtin_amdgcn_mfma_f32_16x16x32_bf16(cvt8v(a##sl, b##sl), w[s], acc, 0, 0, 0);

    f32x4 a0, a1, a2, a3, b0, b1, b2, b3;
    f32x4 acc = {0.f, 0.f, 0.f, 0.f};
    float sreg = 0.0f;

    // prologue for chunk 0: 4 pairs in flight (one per slot)
    const float* base = src + (size_t)(blockRow0 + l15) * kD + lhi * 8;
    GLD2(a0, b0, 0) GLD2(a1, b1, 128) GLD2(a2, b2, 256) GLD2(a3, b3, 384)

    for (int c = 0; c < 4; ++c) {
        MSTEP(0, 0)  MSTEP(1, 1)  MSTEP(2, 2)  MSTEP(3, 3)
        MSTEP(4, 0)  MSTEP(5, 1)  MSTEP(6, 2)  MSTEP(7, 3)
        MSTEP(8, 0)  MSTEP(9, 1)  MSTEP(10, 2) MSTEP(11, 3)
        MSTEPF(12, 0, 6) MSTEPF(13, 1, 4) MSTEPF(14, 2, 2) MSTEPF(15, 3, 0)

        // issue next chunk's prologue NOW -- stays in flight across the barriers
        if (c < 3) {
            base = src + (size_t)(blockRow0 + (c + 1) * 16 + l15) * kD + lhi * 8;
            GLD2(a0, b0, 0) GLD2(a1, b1, 128) GLD2(a2, b2, 256) GLD2(a3, b3, 384)
        }

        // combine: K publishes, V multiplies. lgkmcnt-only waits -- vmcnt
        // (the prefetch) is NOT drained by these barriers.
        if (role == 0) *(f32x4*)&ksh[jt][ln][0] = acc;
        asm volatile("s_waitcnt lgkmcnt(0)" ::: "memory");
        __builtin_amdgcn_s_barrier();
        if (role == 1) {
            f32x4 kk = *(const f32x4*)&ksh[jt][ln][0];
            #pragma unroll
            for (int i = 0; i < 4; ++i)
                sreg += (kk[i] + bk) * (acc[i] + bv);
        }
        asm volatile("s_waitcnt lgkmcnt(0)" ::: "memory");
        __builtin_amdgcn_s_barrier();
        acc[0] = 0.f; acc[1] = 0.f; acc[2] = 0.f; acc[3] = 0.f;
    }
#undef MSTEP
#undef MSTEPF
#undef WAITV
#undef GLD2

    if (role == 1) {
        sreg += __shfl_xor(sreg, 16);
        sreg += __shfl_xor(sreg, 32);
        if (lhi == 0) {
            int bidx = blockRow0 >> 12;   // / kN
            atomicAdd(&S[bidx * kBD + jrow], sreg);
        }
    }
}

// Fused tail: 64 blocks; each block redundantly computes S->Bsum->ms->ext->LN
// for its batch b (tiny), then produces its 64-wide slice of out = normed.Wo^T + bo.
__global__ __launch_bounds__(256)
void lbm_tail(const float* __restrict__ S,    const float* __restrict__ query,
              const float* __restrict__ Wbc,  const float* __restrict__ bbc,
              const float* __restrict__ Wuq,  const float* __restrict__ buq,
              const float* __restrict__ Wue,  const float* __restrict__ bue,
              const float* __restrict__ ln_g, const float* __restrict__ ln_b,
              const float* __restrict__ Wo,   const float* __restrict__ bo,
              float* __restrict__ out)
{
    const int b = blockIdx.x >> 3;
    const int s = blockIdx.x & 7;          // 64-wide output slice
    const int t = threadIdx.x;

    __shared__ float shS[kBD];
    __shared__ float shB[kD];
    __shared__ float shMs[kBD];
    __shared__ float shN[kD];
    __shared__ float redT[4][kBD];
    __shared__ float redQ[4][kBD];
    __shared__ float redLN[8];
    __shared__ float s_mu, s_rs;

    if (t < kBD) shS[t] = S[b * kBD + t];
    __syncthreads();

    // Bsum[d] = sum_j S[j]*Wbc[d,j] + n*bbc[d]
    for (int d = t; d < kD; d += 256) {
        const float4* wr = (const float4*)(Wbc + d * kBD);
        float acc = 0.f;
        #pragma unroll
        for (int q4 = 0; q4 < 16; ++q4) {
            float4 w = wr[q4];
            acc += w.x * shS[q4*4+0] + w.y * shS[q4*4+1]
                 + w.z * shS[q4*4+2] + w.w * shS[q4*4+3];
        }
        shB[d] = acc + (float)kN * bbc[d];
    }
    __syncthreads();

    // t[jj] = Bsum.Wuq[jj,:] + n*buq ; q[jj] = query.Wuq[jj,:] + buq ; ms = q*t
    {
        const int jj = t & 63, qq = t >> 6;
        const float4* wr = (const float4*)(Wuq + jj * kD + qq * 128);
        const float4* qr = (const float4*)(query + b * kD + qq * 128);
        const float4* br = (const float4*)(shB + qq * 128);
        float at = 0.f, aq = 0.f;
        #pragma unroll
        for (int i = 0; i < 32; ++i) {
            float4 w = wr[i]; float4 bb = br[i]; float4 qv = qr[i];
            at += w.x*bb.x + w.y*bb.y + w.z*bb.z + w.w*bb.w;
            aq += w.x*qv.x + w.y*qv.y + w.z*qv.z + w.w*qv.w;
        }
        redT[qq][jj] = at; redQ[qq][jj] = aq;
    }
    __syncthreads();
    if (t < kBD) {
        float tv = redT[0][t] + redT[1][t] + redT[2][t] + redT[3][t] + (float)kN * buq[t];
        float qv = redQ[0][t] + redQ[1][t] + redQ[2][t] + redQ[3][t] + buq[t];
        shMs[t] = tv * qv;
    }
    __syncthreads();

    // ext[d] -> ret -> LN stats
    float lsum = 0.f, lsq = 0.f;
    for (int d = t; d < kD; d += 256) {
        const float4* wr = (const float4*)(Wue + d * kBD);
        float acc = 0.f;
        #pragma unroll
        for (int q4 = 0; q4 < 16; ++q4) {
            float4 w = wr[q4];
            acc += w.x * shMs[q4*4+0] + w.y * shMs[q4*4+1]
                 + w.z * shMs[q4*4+2] + w.w * shMs[q4*4+3];
        }
        float ret = (acc + (float)kN * bue[d]) * (1.0f / 64.0f);
        shN[d] = ret;
        lsum += ret; lsq += ret * ret;
    }
    #pragma unroll
    for (int m = 1; m < 64; m <<= 1) {
        lsum += __shfl_xor(lsum, m);
        lsq  += __shfl_xor(lsq, m);
    }
    if ((t & 63) == 0) { redLN[t >> 6] = lsum; redLN[4 + (t >> 6)] = lsq; }
    __syncthreads();
    if (t == 0) {
        float s0 = redLN[0] + redLN[1] + redLN[2] + redLN[3];
        float s1 = redLN[4] + redLN[5] + redLN[6] + redLN[7];
        float mu = s0 / (float)kD;
        float var = s1 / (float)kD - mu * mu;
        s_mu = mu;
        s_rs = rsqrtf(var + 1e-5f);
    }
    __syncthreads();
    {
        float mu = s_mu, rs = s_rs;
        for (int d = t; d < kD; d += 256)
            shN[d] = (shN[d] - mu) * rs * ln_g[d] + ln_b[d];
    }
    __syncthreads();

    // out slice: d = s*64 + t/4, quarter q = t&3 over the 512-dot
    {
        const int d = s * 64 + (t >> 2);
        const int q = t & 3;
        const float4* wr = (const float4*)(Wo + d * kD + q * 128);
        const float4* nr = (const float4*)(shN + q * 128);
        float acc = 0.f;
        #pragma unroll
        for (int i = 0; i < 32; ++i) {
            float4 w = wr[i]; float4 nv = nr[i];
            acc += w.x*nv.x + w.y*nv.y + w.z*nv.z + w.w*nv.w;
        }
        acc += __shfl_xor(acc, 1);
        acc += __shfl_xor(acc, 2);
        if (q == 0) out[b * kD + d] = acc + bo[d];
    }
}

extern "C" void kernel_launch(void* const* d_in, const int* in_sizes, int n_in,
                              void* d_out, int out_size, void* d_ws, size_t ws_size,
                              hipStream_t stream) {
    const float* keys   = (const float*)d_in[0];
    const float* values = (const float*)d_in[1];
    const float* query  = (const float*)d_in[2];
    const float* Wbk    = (const float*)d_in[3];
    const float* bbk    = (const float*)d_in[4];
    const float* Wbv    = (const float*)d_in[5];
    const float* bbv    = (const float*)d_in[6];
    const float* Wbc    = (const float*)d_in[7];
    const float* bbc    = (const float*)d_in[8];
    const float* Wuq    = (const float*)d_in[9];
    const float* buq    = (const float*)d_in[10];
    const float* Wue    = (const float*)d_in[11];
    const float* bue    = (const float*)d_in[12];
    const float* ln_g   = (const float*)d_in[13];
    const float* ln_b   = (const float*)d_in[14];
    const float* Wo     = (const float*)d_in[15];
    const float* bo     = (const float*)d_in[16];

    // ws layout: S[8][64] f32 (2 KB), wsk[64*512] bf16 (64 KB), wsv[64*512] bf16 (64 KB)
    float*  Sacc = (float*)d_ws;
    __bf16* wsk  = (__bf16*)((char*)d_ws + 2048);
    __bf16* wsv  = wsk + kBD * kD;
    float*  out  = (float*)d_out;

    lbm_prep<<<dim3(33), dim3(256), 0, stream>>>(Wbk, Wbv, wsk, wsv, Sacc);

    const int nblocks = (kB * kN) / 64;   // 512 blocks x 512 threads = 2 blocks/CU
    lbm_bind<<<dim3(nblocks), dim3(512), 0, stream>>>(keys, values, wsk, wsv, bbk, bbv, Sacc);
    lbm_tail<<<dim3(kB * 8), dim3(256), 0, stream>>>(Sacc, query, Wbc, bbc, Wuq, buq,
                                                     Wue, bue, ln_g, ln_b, Wo, bo, out);
}

// Round 9
// 56.885 us; speedup vs baseline: 1.6672x; 1.6672x over previous
//
#include <hip/hip_runtime.h>
#include <hip/hip_bf16.h>

typedef __bf16 bf16x8 __attribute__((ext_vector_type(8)));
typedef __bf16 bf16x4 __attribute__((ext_vector_type(4)));
typedef float  f32x4  __attribute__((ext_vector_type(4)));

constexpr int kD  = 512;
constexpr int kBD = 64;
constexpr int kN  = 4096;
constexpr int kB  = 8;

constexpr int BROWS = 32;   // rows per block -> grid 1024 (4 blocks/CU)
constexpr int NPH   = 8;    // d-units of 64 floats (staged 32r x 64d x {K,V} = 16 KB/phase)

typedef const __attribute__((address_space(1))) void* gas_t;
typedef __attribute__((address_space(3))) void*       las_t;

static __device__ __forceinline__ void gload16(const void* g, void* l) {
    __builtin_amdgcn_global_load_lds((gas_t)g, (las_t)l, 16, 0, 0);
}

__device__ __forceinline__ bf16x8 cvt8(float4 a, float4 b) {
    bf16x8 r;
    r[0] = (__bf16)a.x; r[1] = (__bf16)a.y; r[2] = (__bf16)a.z; r[3] = (__bf16)a.w;
    r[4] = (__bf16)b.x; r[5] = (__bf16)b.y; r[6] = (__bf16)b.z; r[7] = (__bf16)b.w;
    return r;
}

// Prep: Wbk/Wbv fp32 -> bf16 ws images (blocks 0..31); block 32 zeroes S.
__global__ __launch_bounds__(256)
void lbm_prep(const float* __restrict__ Wbk, const float* __restrict__ Wbv,
              __bf16* __restrict__ wsk, __bf16* __restrict__ wsv,
              float* __restrict__ S)
{
    const int bid = blockIdx.x, t = threadIdx.x;
    if (bid < 32) {
        int i = (bid * 256 + t) * 4;
        float4 a = *(const float4*)(Wbk + i);
        float4 b = *(const float4*)(Wbv + i);
        bf16x4 ka, vb;
        ka[0]=(__bf16)a.x; ka[1]=(__bf16)a.y; ka[2]=(__bf16)a.z; ka[3]=(__bf16)a.w;
        vb[0]=(__bf16)b.x; vb[1]=(__bf16)b.y; vb[2]=(__bf16)b.z; vb[3]=(__bf16)b.w;
        *(bf16x4*)(wsk + i) = ka;
        *(bf16x4*)(wsv + i) = vb;
    } else {
        S[t * 2] = 0.f; S[t * 2 + 1] = 0.f;
    }
}

// S[b,j] = sum_n (keys[b,n,:].Wbk[j,:] + bbk[j]) * (values[b,n,:].Wbv[j,:] + bbv[j])
//
// R5 structure (proven 5.9 TB/s aggregate VMEM) with HALF the weight frags
// resident in registers: d-units 0-3 preloaded once per block (16 frags =
// 64 VGPR, pinned), units 4-7 streamed from the L2-hot bf16 image as before.
// Total VMEM bytes: 268 MB -> 201 MB. Grid/LDS/pipeline untouched.
// XCD-aware bijective block swizzle: each XCD owns one contiguous batch.
__global__ __launch_bounds__(256, 4)
void lbm_bind(const float* __restrict__ keys, const float* __restrict__ values,
              const __bf16* __restrict__ wsk, const __bf16* __restrict__ wsv,
              const float* __restrict__ bbk,  const float* __restrict__ bbv,
              float* __restrict__ S)
{
    __shared__ float lds[2][2][16 * 128];   // [buf][K/V][32r x 64d as 16x128] = 32 KB

    const int tid = threadIdx.x;
    const int wv  = tid >> 6;
    const int ln  = tid & 63;
    const int l15 = ln & 15;
    const int lhi = ln >> 4;
    const int sw  = l15 & 7;             // row XOR swizzle key
    const int jrow = wv * 16 + l15;      // weight row (j) for B-operand
    const int dk   = lhi * 8;

    // XCD-aware bijective swizzle (nwg=1024, 8 XCDs -> 128 contiguous blocks/XCD)
    const int bid = blockIdx.x;
    const int swzb = (bid & 7) * 128 + (bid >> 3);
    const int blockRow0 = swzb * BROWS;

    // STAGE phase p into buf (p&1): rows 0..31, d-range [p*64, p*64+64).
    // dest granule = tid (linear); source granule col XOR-swizzled per row.
#define STAGE(p)                                                              \
    {                                                                         \
        _Pragma("unroll")                                                     \
        for (int i_ = 0; i_ < 2; ++i_) {                                      \
            int g_  = i_ * 256 + tid;      /* granule 0..511 */               \
            int r_  = g_ >> 4;             /* row 0..31 */                    \
            int gl_ = g_ & 15;             /* dest granule col in 64d run */  \
            int gs_ = gl_ ^ (r_ & 7);      /* swizzled source granule */      \
            size_t so_ = (size_t)(blockRow0 + r_) * kD + (p) * 64 + gs_ * 4;  \
            gload16(keys   + so_, &lds[(p) & 1][0][g_ * 4]);                  \
            gload16(values + so_, &lds[(p) & 1][1][g_ * 4]);                  \
        }                                                                     \
    }

    STAGE(0)

    // ---- resident weight frags for d-units 0..3 (16 frags = 64 VGPR) ----
    bf16x8 wrk[4][2], wrv[4][2];
    #pragma unroll
    for (int u = 0; u < 4; ++u) {
        wrk[u][0] = *(const bf16x8*)(wsk + jrow * kD + u * 64 + dk);
        wrk[u][1] = *(const bf16x8*)(wsk + jrow * kD + u * 64 + 32 + dk);
        wrv[u][0] = *(const bf16x8*)(wsv + jrow * kD + u * 64 + dk);
        wrv[u][1] = *(const bf16x8*)(wsv + jrow * kD + u * 64 + 32 + dk);
    }
    #pragma unroll
    for (int u = 0; u < 4; ++u) {
        asm volatile("" : "+v"(wrk[u][0]), "+v"(wrk[u][1]),
                          "+v"(wrv[u][0]), "+v"(wrv[u][1]));
    }
    const float bk = bbk[jrow];
    const float bv = bbv[jrow];

    __syncthreads();   // unit 0 resident

    // each wave handles BOTH 16-row chunks of the staged unit for its j-tile
    f32x4 kacc[2] = {{0.f,0.f,0.f,0.f},{0.f,0.f,0.f,0.f}};
    f32x4 vacc[2] = {{0.f,0.f,0.f,0.f},{0.f,0.f,0.f,0.f}};

    #pragma unroll
    for (int p = 0; p < NPH; ++p) {
        if (p + 1 < NPH) STAGE(p + 1)          // next unit in flight under compute

        const int buf = p & 1;

        bf16x8 wk0, wk1, wv0, wv1;
        if (p < 4) {                            // resident (compile-time index)
            wk0 = wrk[p][0]; wk1 = wrk[p][1];
            wv0 = wrv[p][0]; wv1 = wrv[p][1];
        } else {                                // streamed from L2-hot image
            wk0 = *(const bf16x8*)(wsk + jrow * kD + p * 64 + dk);
            wk1 = *(const bf16x8*)(wsk + jrow * kD + p * 64 + 32 + dk);
            wv0 = *(const bf16x8*)(wsv + jrow * kD + p * 64 + dk);
            wv1 = *(const bf16x8*)(wsv + jrow * kD + p * 64 + 32 + dk);
        }

        #pragma unroll
        for (int ch = 0; ch < 2; ++ch) {
            const int rowA = ch * 16 + l15;     // row within staged unit
            const int swr  = rowA & 7;
            const float* bK = &lds[buf][0][0];
            const float* bV = &lds[buf][1][0];

            // granules within the 16-granule (64-float) row run
            const int gc0 = lhi * 2;            // d-step 0 of this unit
            const int o00 = rowA * 64 + ((gc0 ^ swr) << 2);
            const int o01 = rowA * 64 + (((gc0 + 1) ^ swr) << 2);
            const int gc1 = 8 + lhi * 2;        // d-step 1
            const int o10 = rowA * 64 + ((gc1 ^ swr) << 2);
            const int o11 = rowA * 64 + (((gc1 + 1) ^ swr) << 2);

            float4 a, b;
            a = *(const float4*)&bK[o00]; b = *(const float4*)&bK[o01];
            kacc[ch] = __builtin_amdgcn_mfma_f32_16x16x32_bf16(cvt8(a, b), wk0, kacc[ch], 0, 0, 0);
            a = *(const float4*)&bV[o00]; b = *(const float4*)&bV[o01];
            vacc[ch] = __builtin_amdgcn_mfma_f32_16x16x32_bf16(cvt8(a, b), wv0, vacc[ch], 0, 0, 0);
            a = *(const float4*)&bK[o10]; b = *(const float4*)&bK[o11];
            kacc[ch] = __builtin_amdgcn_mfma_f32_16x16x32_bf16(cvt8(a, b), wk1, kacc[ch], 0, 0, 0);
            a = *(const float4*)&bV[o10]; b = *(const float4*)&bV[o11];
            vacc[ch] = __builtin_amdgcn_mfma_f32_16x16x32_bf16(cvt8(a, b), wv1, vacc[ch], 0, 0, 0);
        }

        __syncthreads();   // staged p+1 visible; readers done before buf reuse
    }
#undef STAGE

    // combine projections over both 16-row chunks
    float sreg = 0.0f;
    #pragma unroll
    for (int ch = 0; ch < 2; ++ch)
        #pragma unroll
        for (int i = 0; i < 4; ++i)
            sreg += (kacc[ch][i] + bk) * (vacc[ch][i] + bv);

    // reduce over the 4 row-groups (C/D rows live in lanes ^16, ^32)
    sreg += __shfl_xor(sreg, 16);
    sreg += __shfl_xor(sreg, 32);
    if (lhi == 0) {
        int bidx = blockRow0 >> 12;   // / kN
        atomicAdd(&S[bidx * kBD + jrow], sreg);
    }
}

// Fused tail: 64 blocks; each block redundantly computes S->Bsum->ms->ext->LN
// for its batch b (tiny), then produces its 64-wide slice of out = normed.Wo^T + bo.
__global__ __launch_bounds__(256)
void lbm_tail(const float* __restrict__ S,    const float* __restrict__ query,
              const float* __restrict__ Wbc,  const float* __restrict__ bbc,
              const float* __restrict__ Wuq,  const float* __restrict__ buq,
              const float* __restrict__ Wue,  const float* __restrict__ bue,
              const float* __restrict__ ln_g, const float* __restrict__ ln_b,
              const float* __restrict__ Wo,   const float* __restrict__ bo,
              float* __restrict__ out)
{
    const int b = blockIdx.x >> 3;
    const int s = blockIdx.x & 7;          // 64-wide output slice
    const int t = threadIdx.x;

    __shared__ float shS[kBD];
    __shared__ float shB[kD];
    __shared__ float shMs[kBD];
    __shared__ float shN[kD];
    __shared__ float redT[4][kBD];
    __shared__ float redQ[4][kBD];
    __shared__ float redLN[8];
    __shared__ float s_mu, s_rs;

    if (t < kBD) shS[t] = S[b * kBD + t];
    __syncthreads();

    // Bsum[d] = sum_j S[j]*Wbc[d,j] + n*bbc[d]
    for (int d = t; d < kD; d += 256) {
        const float4* wr = (const float4*)(Wbc + d * kBD);
        float acc = 0.f;
        #pragma unroll
        for (int q4 = 0; q4 < 16; ++q4) {
            float4 w = wr[q4];
            acc += w.x * shS[q4*4+0] + w.y * shS[q4*4+1]
                 + w.z * shS[q4*4+2] + w.w * shS[q4*4+3];
        }
        shB[d] = acc + (float)kN * bbc[d];
    }
    __syncthreads();

    // t[jj] = Bsum.Wuq[jj,:] + n*buq ; q[jj] = query.Wuq[jj,:] + buq ; ms = q*t
    {
        const int jj = t & 63, qq = t >> 6;
        const float4* wr = (const float4*)(Wuq + jj * kD + qq * 128);
        const float4* qr = (const float4*)(query + b * kD + qq * 128);
        const float4* br = (const float4*)(shB + qq * 128);
        float at = 0.f, aq = 0.f;
        #pragma unroll
        for (int i = 0; i < 32; ++i) {
            float4 w = wr[i]; float4 bb = br[i]; float4 qv = qr[i];
            at += w.x*bb.x + w.y*bb.y + w.z*bb.z + w.w*bb.w;
            aq += w.x*qv.x + w.y*qv.y + w.z*qv.z + w.w*qv.w;
        }
        redT[qq][jj] = at; redQ[qq][jj] = aq;
    }
    __syncthreads();
    if (t < kBD) {
        float tv = redT[0][t] + redT[1][t] + redT[2][t] + redT[3][t] + (float)kN * buq[t];
        float qv = redQ[0][t] + redQ[1][t] + redQ[2][t] + redQ[3][t] + buq[t];
        shMs[t] = tv * qv;
    }
    __syncthreads();

    // ext[d] -> ret -> LN stats
    float lsum = 0.f, lsq = 0.f;
    for (int d = t; d < kD; d += 256) {
        const float4* wr = (const float4*)(Wue + d * kBD);
        float acc = 0.f;
        #pragma unroll
        for (int q4 = 0; q4 < 16; ++q4) {
            float4 w = wr[q4];
            acc += w.x * shMs[q4*4+0] + w.y * shMs[q4*4+1]
                 + w.z * shMs[q4*4+2] + w.w * shMs[q4*4+3];
        }
        float ret = (acc + (float)kN * bue[d]) * (1.0f / 64.0f);
        shN[d] = ret;
        lsum += ret; lsq += ret * ret;
    }
    #pragma unroll
    for (int m = 1; m < 64; m <<= 1) {
        lsum += __shfl_xor(lsum, m);
        lsq  += __shfl_xor(lsq, m);
    }
    if ((t & 63) == 0) { redLN[t >> 6] = lsum; redLN[4 + (t >> 6)] = lsq; }
    __syncthreads();
    if (t == 0) {
        float s0 = redLN[0] + redLN[1] + redLN[2] + redLN[3];
        float s1 = redLN[4] + redLN[5] + redLN[6] + redLN[7];
        float mu = s0 / (float)kD;
        float var = s1 / (float)kD - mu * mu;
        s_mu = mu;
        s_rs = rsqrtf(var + 1e-5f);
    }
    __syncthreads();
    {
        float mu = s_mu, rs = s_rs;
        for (int d = t; d < kD; d += 256)
            shN[d] = (shN[d] - mu) * rs * ln_g[d] + ln_b[d];
    }
    __syncthreads();

    // out slice: d = s*64 + t/4, quarter q = t&3 over the 512-dot
    {
        const int d = s * 64 + (t >> 2);
        const int q = t & 3;
        const float4* wr = (const float4*)(Wo + d * kD + q * 128);
        const float4* nr = (const float4*)(shN + q * 128);
        float acc = 0.f;
        #pragma unroll
        for (int i = 0; i < 32; ++i) {
            float4 w = wr[i]; float4 nv = nr[i];
            acc += w.x*nv.x + w.y*nv.y + w.z*nv.z + w.w*nv.w;
        }
        acc += __shfl_xor(acc, 1);
        acc += __shfl_xor(acc, 2);
        if (q == 0) out[b * kD + d] = acc + bo[d];
    }
}

extern "C" void kernel_launch(void* const* d_in, const int* in_sizes, int n_in,
                              void* d_out, int out_size, void* d_ws, size_t ws_size,
                              hipStream_t stream) {
    const float* keys   = (const float*)d_in[0];
    const float* values = (const float*)d_in[1];
    const float* query  = (const float*)d_in[2];
    const float* Wbk    = (const float*)d_in[3];
    const float* bbk    = (const float*)d_in[4];
    const float* Wbv    = (const float*)d_in[5];
    const float* bbv    = (const float*)d_in[6];
    const float* Wbc    = (const float*)d_in[7];
    const float* bbc    = (const float*)d_in[8];
    const float* Wuq    = (const float*)d_in[9];
    const float* buq    = (const float*)d_in[10];
    const float* Wue    = (const float*)d_in[11];
    const float* bue    = (const float*)d_in[12];
    const float* ln_g   = (const float*)d_in[13];
    const float* ln_b   = (const float*)d_in[14];
    const float* Wo     = (const float*)d_in[15];
    const float* bo     = (const float*)d_in[16];

    // ws layout: S[8][64] f32 (2 KB), wsk[64*512] bf16 (64 KB), wsv[64*512] bf16 (64 KB)
    float*  Sacc = (float*)d_ws;
    __bf16* wsk  = (__bf16*)((char*)d_ws + 2048);
    __bf16* wsv  = wsk + kBD * kD;
    float*  out  = (float*)d_out;

    lbm_prep<<<dim3(33), dim3(256), 0, stream>>>(Wbk, Wbv, wsk, wsv, Sacc);

    const int nblocks = (kB * kN) / BROWS;   // 1024 -> 4 blocks/CU
    lbm_bind<<<dim3(nblocks), dim3(256), 0, stream>>>(keys, values, wsk, wsv, bbk, bbv, Sacc);
    lbm_tail<<<dim3(kB * 8), dim3(256), 0, stream>>>(Sacc, query, Wbc, bbc, Wuq, buq,
                                                     Wue, bue, ln_g, ln_b, Wo, bo, out);
}